// Round 8
// baseline (189.899 us; speedup 1.0000x reference)
//
#include <hip/hip_runtime.h>

// CPRPackedLinear: out(64x11008) = xperm[:, :1024] @ deq6(W_high) + xperm[:, 1024:] @ deq5(W_low) + bias
//
// R8 = R7 (compaction theory) hardened:
//  - int32 "packed" weights carry only their LOW BYTE -> 118.3 MB of traffic for
//    29.6 MB of data, served at ~2.4 TB/s by the scattered pattern while a pure
//    stream hits 6.7 TB/s. compact_w streams the 118 MB linearly and emits
//    29.6 MB tile-major bytes; gemm then reads contiguous 5-6 KB steps of
//    L3-resident data via global_load_lds + 3-buf rotation + counted vmcnt.
//  - NEW safety: 3-tier ws_size dispatch (52.7 MB / 30.1 MB / 0.5 MB); R7's else
//    branch could write 30 MB OOB if ws in [23,52.7) MB -> likely cause of the
//    container fault. Tier 3 = R4 barrier-free direct gemm (verified passing).
//  - NEW: per-row 16B*(row%8) rotation in the compact layout kills the 4-way
//    LDS bank conflict on dequant byte reads (row stride 128B aligned banks);
//    linear global_load_lds copy is unaffected (source-side permutation, G21).

#define NFEAT 11008
#define KTOT  4096

#define HTILE 98304u     // 768 rows * 128 B
#define LTILE 245760u    // 1920 rows * 128 B
#define LBASE 8454144u   // 86 * HTILE
#define CSIZE 29589504u  // LBASE + 86 * LTILE

typedef _Float16 half8 __attribute__((ext_vector_type(8)));
typedef float    f32x4 __attribute__((ext_vector_type(4)));
typedef int      int2v __attribute__((ext_vector_type(2)));

#define GLOAD16(g, l) __builtin_amdgcn_global_load_lds(                         \
    (const __attribute__((address_space(1))) unsigned int*)(g),                 \
    (__attribute__((address_space(3))) unsigned int*)(l), 16, 0, 0)
#define WAITV(N) asm volatile("s_waitcnt vmcnt(" #N ")" ::: "memory")
#define FENCE()  asm volatile("" ::: "memory")

// ---------------- prep: x_perm -> fp16 in MFMA A-fragment layout ----------------
// xfrag flat idx = ((s*4 + mt)*64 + lane)*8 + j
//   holds x[m = mt*16 + (lane&15)][ col_indices[k = s*32 + (lane>>4)*8 + j] ]
__global__ __launch_bounds__(256) void prep_xfrag(const float* __restrict__ x,
                                                  const int* __restrict__ col,
                                                  _Float16* __restrict__ xfrag) {
    int idx = blockIdx.x * 256 + threadIdx.x;          // 0..262143
    int j  = idx & 7;
    int l  = (idx >> 3) & 63;
    int mt = (idx >> 9) & 3;
    int s  = idx >> 11;
    int k  = s * 32 + ((l >> 4) << 3) + j;
    int m  = mt * 16 + (l & 15);
    xfrag[idx] = (_Float16)x[m * KTOT + col[k]];
}

// ---------------- compact: low-byte extraction + tile-major relayout ----------------
// grid (86, 672) x 256 thr. y<192: high rows 4y..4y+3; else low rows 4(y-192)..
// Reads: wave-linear int2 (512 B contiguous per wave). Writes: row bytes ROTATED
// by 16*(row%8) within the 128-B row (bank-conflict-free dequant reads later).
__global__ __launch_bounds__(256) void compact_w(const int* __restrict__ Wh,
                                                 const int* __restrict__ Wl,
                                                 unsigned char* __restrict__ C) {
    const int bx  = blockIdx.x;
    const int y   = blockIdx.y;
    const int sub = threadIdx.x >> 6;
    const int l2  = (threadIdx.x & 63) * 2;
    const int*     src;
    unsigned char* dst;
    int r;
    if (y < 192) {
        r   = y * 4 + sub;
        src = Wh + (size_t)r * NFEAT + bx * 128;
        dst = C + (size_t)bx * HTILE + r * 128;
    } else {
        r   = (y - 192) * 4 + sub;
        src = Wl + (size_t)r * NFEAT + bx * 128;
        dst = C + LBASE + (size_t)bx * LTILE + r * 128;
    }
    int2v v = *(const int2v*)(src + l2);
    unsigned short p = (unsigned short)((v.x & 255) | ((v.y & 255) << 8));
    const int pos = (l2 + ((r & 7) << 4)) & 127;        // rotated, even -> no wrap split
    *(unsigned short*)(dst + pos) = p;
}

// ---------------- main GEMM (compacted weights) ----------------
// grid (86, 8): 128-col tiles x 512-k chunks (kc 0..1 high, 2..7 low).
// block = 256 = 4 waves; wave w owns cols [n0+32w, +32) (2 nt), rows 0..63.
// 8 steps of 64-k; per step stage 6KB(high)/5KB(low) W (contiguous) + 8KB A.
__global__ __launch_bounds__(256, 3) void gemm_kernel(const unsigned char* __restrict__ C,
                                                      const float* __restrict__ sh,
                                                      const float* __restrict__ sl,
                                                      const _Float16* __restrict__ xfrag,
                                                      float* __restrict__ dst,
                                                      int atomic_mode) {
    const int bx   = blockIdx.x;
    const int kc   = blockIdx.y;
    const int lane = threadIdx.x & 63;
    const int wave = threadIdx.x >> 6;                  // 0..3
    const int n0   = bx * 128;
    const int o    = lane >> 4;                         // k-octet 0..3
    const int cc   = wave * 32 + (lane & 15);           // block-local col (nt=0)

    __shared__ __align__(16) unsigned char Wb[3][6144];
    __shared__ __align__(16) _Float16 Ab[3][8][512];    // 8 frags = ss*4+mt
    __shared__ float sLds[4][128];                      // 4 scale groups x 128 cols

    const bool high = (kc < 2);

    // ---- stage scales to LDS (runtime-group-indexable) ----
    {
        const float* sp = high ? sh + (size_t)(kc * 4) * NFEAT
                               : sl + (size_t)((kc - 2) * 4) * NFEAT;
        for (int i = threadIdx.x; i < 512; i += 256)
            sLds[i >> 7][i & 127] = sp[(size_t)(i >> 7) * NFEAT + n0 + (i & 127)];
    }

    f32x4 acc[4][2];
#pragma unroll
    for (int i = 0; i < 4; ++i)
#pragma unroll
        for (int j = 0; j < 2; ++j) acc[i][j] = (f32x4){0.f, 0.f, 0.f, 0.f};

    __syncthreads();                                    // scales visible; vmcnt drained

    const unsigned char* cbase = high
        ? C + (size_t)bx * HTILE + (size_t)kc * 49152
        : C + LBASE + (size_t)bx * LTILE + (size_t)(kc - 2) * 40960;
    const int stepb = high ? 6144 : 5120;

    // Per-wave loads: high {4,4,3,3}, low {4,3,3,3} (W spans of 1KB + 2 A frags).
    auto stage = [&](int t, int buf) {
        const unsigned char* wsrc = cbase + (size_t)t * stepb;
        GLOAD16(wsrc + wave * 1024 + lane * 16, &Wb[buf][wave * 1024]);
        if (high) {
            if (wave < 2) GLOAD16(wsrc + (wave + 4) * 1024 + lane * 16,
                                  &Wb[buf][(wave + 4) * 1024]);
        } else {
            if (wave == 0) GLOAD16(wsrc + 4 * 1024 + lane * 16, &Wb[buf][4 * 1024]);
        }
        const int sgb = kc * 16 + t * 2;                // 32-k step index (ss=0)
        GLOAD16(xfrag + ((size_t)(sgb * 4 + wave) * 64 + lane) * 8,
                &Ab[buf][wave][0]);
        GLOAD16(xfrag + ((size_t)((sgb + 1) * 4 + wave) * 64 + lane) * 8,
                &Ab[buf][4 + wave][0]);
    };

    // rotated byte fetch: row R (in-slab), col c; rotation uses R&7 (slab bases = 0 mod 8)
    auto LB = [&](int bi, int R, int c) -> int {
        return (int)Wb[bi][R * 128 + ((c + ((R & 7) << 4)) & 127)];
    };

    stage(0, 0);
    stage(1, 1);

    const bool cnt4 = high ? (wave < 2) : (wave == 0);
    for (int t = 0; t < 8; ++t) {
        if (t < 7) { if (cnt4) WAITV(4); else WAITV(3); }   // retire batch t only
        else       { WAITV(0); }
        __builtin_amdgcn_s_barrier();
        FENCE();
        if (t + 2 < 8) stage(t + 2, (t + 2) % 3);
        const int bi = t % 3;

#pragma unroll
        for (int ss = 0; ss < 2; ++ss) {
            const int g = (t * 2 + ss) >> 2;            // scale group
#pragma unroll
            for (int nt = 0; nt < 2; ++nt) {
                const int c = cc + nt * 16;
                const float s = sLds[g][c];
                half8 bf;
                if (high) {
                    const int rb = ss * 24 + 6 * o;
                    const int b0 = LB(bi, rb + 0, c);
                    const int b1 = LB(bi, rb + 1, c);
                    const int b2 = LB(bi, rb + 2, c);
                    const int b3 = LB(bi, rb + 3, c);
                    const int b4 = LB(bi, rb + 4, c);
                    const int b5 = LB(bi, rb + 5, c);
                    const int v0 = b0 & 63;
                    const int v1 = ((b0 >> 6) & 3) | ((b1 & 15) << 2);
                    const int v2 = ((b1 >> 4) & 15) | ((b2 & 3) << 4);
                    const int v3 = (b2 >> 2) & 63;
                    const int v4 = b3 & 63;
                    const int v5 = ((b3 >> 6) & 3) | ((b4 & 15) << 2);
                    const int v6 = ((b4 >> 4) & 15) | ((b5 & 3) << 4);
                    const int v7 = (b5 >> 2) & 63;
                    const float moff = -31.0f * s;
                    bf[0] = (_Float16)fmaf((float)v0, s, moff);
                    bf[1] = (_Float16)fmaf((float)v1, s, moff);
                    bf[2] = (_Float16)fmaf((float)v2, s, moff);
                    bf[3] = (_Float16)fmaf((float)v3, s, moff);
                    bf[4] = (_Float16)fmaf((float)v4, s, moff);
                    bf[5] = (_Float16)fmaf((float)v5, s, moff);
                    bf[6] = (_Float16)fmaf((float)v6, s, moff);
                    bf[7] = (_Float16)fmaf((float)v7, s, moff);
                } else {
                    const int rb = ss * 20 + 5 * o;
                    const int b0 = LB(bi, rb + 0, c);
                    const int b1 = LB(bi, rb + 1, c);
                    const int b2 = LB(bi, rb + 2, c);
                    const int b3 = LB(bi, rb + 3, c);
                    const int b4 = LB(bi, rb + 4, c);
                    const int v0 = b0 & 31;
                    const int v1 = ((b0 >> 5) & 7) | ((b1 & 3) << 3);
                    const int v2 = (b1 >> 2) & 31;
                    const int v3 = ((b1 >> 7) & 1) | ((b2 & 15) << 1);
                    const int v4 = ((b2 >> 4) & 15) | ((b3 & 1) << 4);
                    const int v5 = (b3 >> 1) & 31;
                    const int v6 = ((b3 >> 6) & 3) | ((b4 & 7) << 2);
                    const int v7 = (b4 >> 3) & 31;
                    const float moff = -15.0f * s;
                    bf[0] = (_Float16)fmaf((float)v0, s, moff);
                    bf[1] = (_Float16)fmaf((float)v1, s, moff);
                    bf[2] = (_Float16)fmaf((float)v2, s, moff);
                    bf[3] = (_Float16)fmaf((float)v3, s, moff);
                    bf[4] = (_Float16)fmaf((float)v4, s, moff);
                    bf[5] = (_Float16)fmaf((float)v5, s, moff);
                    bf[6] = (_Float16)fmaf((float)v6, s, moff);
                    bf[7] = (_Float16)fmaf((float)v7, s, moff);
                }
#pragma unroll
                for (int mt = 0; mt < 4; ++mt) {
                    half8 a = *(const half8*)&Ab[bi][ss * 4 + mt][lane * 8];
                    acc[mt][nt] = __builtin_amdgcn_mfma_f32_16x16x32_f16(a, bf, acc[mt][nt], 0, 0, 0);
                }
            }
        }
    }

    // ---- epilogue: waves own disjoint cols -> direct store ----
    const int r0 = (lane >> 4) << 2;
    if (atomic_mode) {
#pragma unroll
        for (int mt = 0; mt < 4; ++mt)
#pragma unroll
            for (int nt = 0; nt < 2; ++nt)
#pragma unroll
                for (int r = 0; r < 4; ++r)
                    atomicAdd(&dst[(mt * 16 + r0 + r) * NFEAT + n0 + cc + nt * 16],
                              acc[mt][nt][r]);
    } else {
        float* base = dst + (size_t)kc * 64 * NFEAT;
#pragma unroll
        for (int mt = 0; mt < 4; ++mt)
#pragma unroll
            for (int nt = 0; nt < 2; ++nt)
#pragma unroll
                for (int r = 0; r < 4; ++r)
                    base[(mt * 16 + r0 + r) * NFEAT + n0 + cc + nt * 16] = acc[mt][nt][r];
    }
}

// ---------------- tier-3 fallback: R4 barrier-free direct gemm (atomic) ----------------
// grid (172, 8); wave-independent; reads Wh/Wl directly. Verified passing in R4.
__global__ __launch_bounds__(256, 4) void gemm_direct(const int* __restrict__ Wh,
                                                      const int* __restrict__ Wl,
                                                      const float* __restrict__ sh,
                                                      const float* __restrict__ sl,
                                                      const _Float16* __restrict__ xfrag,
                                                      float* __restrict__ dst) {
    const int n0   = blockIdx.x * 64;
    const int kc   = blockIdx.y;
    const int k0   = kc * 512;
    const int lane = threadIdx.x & 63;
    const int wave = threadIdx.x >> 6;
    const int n  = n0 + wave * 16 + (lane & 15);
    const int kb = (lane >> 4) << 3;

    f32x4 acc[4];
#pragma unroll
    for (int i = 0; i < 4; ++i) acc[i] = (f32x4){0.f, 0.f, 0.f, 0.f};

    if (k0 < 1024) {
        for (int g = 0; g < 4; ++g) {
            const float s    = sh[((k0 >> 7) + g) * NFEAT + n];
            const float moff = -31.0f * s;
#pragma unroll
            for (int st = 0; st < 4; ++st) {
                const int k = k0 + g * 128 + st * 32 + kb;
                const int* bp = Wh + 3 * (k >> 2) * NFEAT + n;
                const int b0 = bp[0];         const int b1 = bp[NFEAT];
                const int b2 = bp[2 * NFEAT]; const int b3 = bp[3 * NFEAT];
                const int b4 = bp[4 * NFEAT]; const int b5 = bp[5 * NFEAT];
                int v0 = b0 & 63;
                int v1 = ((b0 >> 6) & 3) | ((b1 & 15) << 2);
                int v2 = ((b1 >> 4) & 15) | ((b2 & 3) << 4);
                int v3 = (b2 >> 2) & 63;
                int v4 = b3 & 63;
                int v5 = ((b3 >> 6) & 3) | ((b4 & 15) << 2);
                int v6 = ((b4 >> 4) & 15) | ((b5 & 3) << 4);
                int v7 = (b5 >> 2) & 63;
                half8 b;
                b[0] = (_Float16)fmaf((float)v0, s, moff);
                b[1] = (_Float16)fmaf((float)v1, s, moff);
                b[2] = (_Float16)fmaf((float)v2, s, moff);
                b[3] = (_Float16)fmaf((float)v3, s, moff);
                b[4] = (_Float16)fmaf((float)v4, s, moff);
                b[5] = (_Float16)fmaf((float)v5, s, moff);
                b[6] = (_Float16)fmaf((float)v6, s, moff);
                b[7] = (_Float16)fmaf((float)v7, s, moff);
                const int sg = (k0 >> 5) + g * 4 + st;
#pragma unroll
                for (int mt = 0; mt < 4; ++mt) {
                    half8 a = *(const half8*)(xfrag + (((sg * 4 + mt) * 64 + lane) << 3));
                    acc[mt] = __builtin_amdgcn_mfma_f32_16x16x32_f16(a, b, acc[mt], 0, 0, 0);
                }
            }
        }
    } else {
        const int kl0 = k0 - 1024;
        for (int g = 0; g < 4; ++g) {
            const float s    = sl[((kl0 >> 7) + g) * NFEAT + n];
            const float moff = -15.0f * s;
#pragma unroll
            for (int st = 0; st < 4; ++st) {
                const int kl = kl0 + g * 128 + st * 32 + kb;
                const int* bp = Wl + 5 * (kl >> 3) * NFEAT + n;
                const int b0 = bp[0];         const int b1 = bp[NFEAT];
                const int b2 = bp[2 * NFEAT]; const int b3 = bp[3 * NFEAT];
                const int b4 = bp[4 * NFEAT];
                int v0 = b0 & 31;
                int v1 = ((b0 >> 5) & 7) | ((b1 & 3) << 3);
                int v2 = (b1 >> 2) & 31;
                int v3 = ((b1 >> 7) & 1) | ((b2 & 15) << 1);
                int v4 = ((b2 >> 4) & 15) | ((b3 & 1) << 4);
                int v5 = (b3 >> 1) & 31;
                int v6 = ((b3 >> 6) & 3) | ((b4 & 7) << 2);
                int v7 = (b4 >> 3) & 31;
                half8 b;
                b[0] = (_Float16)fmaf((float)v0, s, moff);
                b[1] = (_Float16)fmaf((float)v1, s, moff);
                b[2] = (_Float16)fmaf((float)v2, s, moff);
                b[3] = (_Float16)fmaf((float)v3, s, moff);
                b[4] = (_Float16)fmaf((float)v4, s, moff);
                b[5] = (_Float16)fmaf((float)v5, s, moff);
                b[6] = (_Float16)fmaf((float)v6, s, moff);
                b[7] = (_Float16)fmaf((float)v7, s, moff);
                const int sg = 32 + (kl0 >> 5) + g * 4 + st;
#pragma unroll
                for (int mt = 0; mt < 4; ++mt) {
                    half8 a = *(const half8*)(xfrag + (((sg * 4 + mt) * 64 + lane) << 3));
                    acc[mt] = __builtin_amdgcn_mfma_f32_16x16x32_f16(a, b, acc[mt], 0, 0, 0);
                }
            }
        }
    }

    const int r0 = (lane >> 4) << 2;
#pragma unroll
    for (int mt = 0; mt < 4; ++mt)
#pragma unroll
        for (int r = 0; r < 4; ++r)
            atomicAdd(&dst[(mt * 16 + r0 + r) * NFEAT + n], acc[mt][r]);
}

// ---------------- reduce: out = bias + sum_kc partial[kc] ----------------
__global__ __launch_bounds__(256) void reduce_out(const float* __restrict__ part,
                                                  const float* __restrict__ bias,
                                                  float* __restrict__ out, int nc) {
    const int idx = blockIdx.x * 256 + threadIdx.x;    // 0..176127 (float4 units)
    const int f   = idx * 4;
    const int n   = f % NFEAT;                          // NFEAT % 4 == 0 -> same row
    f32x4 sum = *(const f32x4*)(bias + n);
    for (int c = 0; c < nc; ++c)
        sum += *(const f32x4*)(part + (size_t)c * 704512 + f);
    *(f32x4*)(out + f) = sum;
}

__global__ __launch_bounds__(256) void init_bias(const float* __restrict__ bias,
                                                 float* __restrict__ out) {
    const int idx = blockIdx.x * 256 + threadIdx.x;    // 0..704511
    out[idx] = bias[idx % NFEAT];
}

extern "C" void kernel_launch(void* const* d_in, const int* in_sizes, int n_in,
                              void* d_out, int out_size, void* d_ws, size_t ws_size,
                              hipStream_t stream) {
    const float* x    = (const float*)d_in[0];
    const int*   Wh   = (const int*)d_in[1];
    const int*   Wl   = (const int*)d_in[2];
    const float* sh   = (const float*)d_in[3];
    const float* sl   = (const float*)d_in[4];
    const int*   col  = (const int*)d_in[5];
    const float* bias = (const float*)d_in[6];
    float* out = (float*)d_out;

    _Float16* xfrag = (_Float16*)d_ws;                 // 512 KB
    const size_t xo = 524288;
    const size_t part_bytes = 8ull * 64 * NFEAT * sizeof(float);   // 22,544,384

    prep_xfrag<<<1024, 256, 0, stream>>>(x, col, xfrag);

    if (ws_size >= xo + part_bytes + CSIZE) {
        // tier 1: compact + partials + reduce
        float*         part = (float*)((char*)d_ws + xo);
        unsigned char* C    = (unsigned char*)d_ws + xo + part_bytes;
        compact_w<<<dim3(86, 672), 256, 0, stream>>>(Wh, Wl, C);
        gemm_kernel<<<dim3(86, 8), 256, 0, stream>>>(C, sh, sl, xfrag, part, 0);
        reduce_out<<<688, 256, 0, stream>>>(part, bias, out, 8);
    } else if (ws_size >= xo + CSIZE) {
        // tier 2: compact + atomic accumulate into out
        unsigned char* C = (unsigned char*)d_ws + xo;
        compact_w<<<dim3(86, 672), 256, 0, stream>>>(Wh, Wl, C);
        init_bias<<<2752, 256, 0, stream>>>(bias, out);
        gemm_kernel<<<dim3(86, 8), 256, 0, stream>>>(C, sh, sl, xfrag, out, 1);
    } else {
        // tier 3: no room for C -> direct-read gemm (R4 structure, verified)
        init_bias<<<2752, 256, 0, stream>>>(bias, out);
        gemm_direct<<<dim3(172, 8), 256, 0, stream>>>(Wh, Wl, sh, sl, xfrag, out);
    }
}